// Round 2
// baseline (1657.521 us; speedup 1.0000x reference)
//
#include <hip/hip_runtime.h>
#include <hip/hip_bf16.h>
#include <stdint.h>

// Problem constants (from reference: N=4264, B=256, NG=8, GS=533, SAMPLE_NUM=10)
#define NN 4264
#define BB 256
#define GSZ 533
#define NGRP 8
#define NSWEEP 10
#define NSTEP (NSWEEP * NGRP)
#define DMAX 64        // max row degree (Binomial(4263, 15/4264) ~ Poisson(15); P(deg>64) ~ 1e-18)

struct Keys { unsigned k0[NSTEP]; unsigned k1[NSTEP]; };

// ---- threefry2x32, exactly as JAX (20 rounds, key injections every 4) ----
#define TF_ROUND(x0, x1, r) { x0 += x1; x1 = (x1 << (r)) | (x1 >> (32 - (r))); x1 ^= x0; }
#define TF_BODY(K0, K1, C0, C1, O0, O1) {                                   \
  unsigned ks0 = (K0), ks1 = (K1), ks2 = (K0) ^ (K1) ^ 0x1BD11BDAu;          \
  unsigned x0 = (C0) + ks0, x1 = (C1) + ks1;                                 \
  TF_ROUND(x0, x1, 13) TF_ROUND(x0, x1, 15) TF_ROUND(x0, x1, 26) TF_ROUND(x0, x1, 6)  \
  x0 += ks1; x1 += ks2 + 1u;                                                 \
  TF_ROUND(x0, x1, 17) TF_ROUND(x0, x1, 29) TF_ROUND(x0, x1, 16) TF_ROUND(x0, x1, 24) \
  x0 += ks2; x1 += ks0 + 2u;                                                 \
  TF_ROUND(x0, x1, 13) TF_ROUND(x0, x1, 15) TF_ROUND(x0, x1, 26) TF_ROUND(x0, x1, 6)  \
  x0 += ks0; x1 += ks1 + 3u;                                                 \
  TF_ROUND(x0, x1, 17) TF_ROUND(x0, x1, 29) TF_ROUND(x0, x1, 16) TF_ROUND(x0, x1, 24) \
  x0 += ks1; x1 += ks2 + 4u;                                                 \
  TF_ROUND(x0, x1, 13) TF_ROUND(x0, x1, 15) TF_ROUND(x0, x1, 26) TF_ROUND(x0, x1, 6)  \
  x0 += ks2; x1 += ks0 + 5u;                                                 \
  (O0) = x0; (O1) = x1; }

static void tf_host(unsigned k0, unsigned k1, unsigned c0, unsigned c1,
                    unsigned* o0, unsigned* o1) {
  unsigned a, b;
  TF_BODY(k0, k1, c0, c1, a, b);
  *o0 = a; *o1 = b;
}

__device__ __forceinline__ void tf_dev(unsigned k0, unsigned k1, unsigned c0, unsigned c1,
                                       unsigned& o0, unsigned& o1) {
  TF_BODY(k0, k1, c0, c1, o0, o1);
}

// ---- Build ELL sparse format of J (deterministic, ascending-column order) ----
__global__ __launch_bounds__(256) void build_ell(const float* __restrict__ J,
                                                 int* __restrict__ cols,
                                                 float* __restrict__ vals,
                                                 int* __restrict__ deg) {
  const int row = blockIdx.x;
  const int tid = threadIdx.x;
  __shared__ int s_cnt;
  __shared__ int wcnt[4];
  if (tid == 0) s_cnt = 0;
  __syncthreads();
  const float* Jr = J + (size_t)row * NN;
  for (int base = 0; base < NN; base += 256) {
    const int c = base + tid;
    const float v = (c < NN) ? Jr[c] : 0.0f;
    const bool nz = (v != 0.0f);
    const unsigned long long mask = __ballot(nz);
    const int wave = tid >> 6, lane = tid & 63;
    if (lane == 0) wcnt[wave] = __popcll(mask);
    __syncthreads();
    int off = s_cnt;
    for (int w = 0; w < wave; ++w) off += wcnt[w];
    const int rank = off + __popcll(mask & ((1ull << lane) - 1ull));
    if (nz && rank < DMAX) {
      cols[(size_t)row * DMAX + rank] = c;
      vals[(size_t)row * DMAX + rank] = v;
    }
    __syncthreads();
    if (tid == 0) s_cnt += wcnt[0] + wcnt[1] + wcnt[2] + wcnt[3];
    __syncthreads();
  }
  if (tid == 0) deg[row] = (s_cnt > DMAX) ? DMAX : s_cnt;
}

// ---- Full Gibbs chain: one workgroup per batch row (rows are independent) ----
__global__ __launch_bounds__(256) void gibbs(const float* __restrict__ m0,
                                             const float* __restrict__ H,
                                             const int* __restrict__ groups,
                                             const int* __restrict__ cols,
                                             const float* __restrict__ vals,
                                             const int* __restrict__ deg,
                                             float* __restrict__ out,
                                             Keys keys) {
  __shared__ float m_lds[NN];
  __shared__ float newv[GSZ];
  const int b = blockIdx.x;
  const int tid = threadIdx.x;

  for (int n = tid; n < NN; n += 256) m_lds[n] = m0[(size_t)b * NN + n];
  __syncthreads();

  for (int t = 0; t < NSWEEP; ++t) {
    for (int g = 0; g < NGRP; ++g) {
      const int step = t * NGRP + g;
      const unsigned k0 = keys.k0[step];
      const unsigned k1 = keys.k1[step];
      const int* grp = groups + g * GSZ;

      for (int i = tid; i < GSZ; i += 256) {
        const int node = grp[i];
        const int d = deg[node];
        const int* cp = cols + (size_t)node * DMAX;
        const float* vp = vals + (size_t)node * DMAX;
        double I = (double)H[node];
        for (int k = 0; k < d; ++k) {
          I = fma((double)vp[k], (double)m_lds[cp[k]], I);
        }
        const double th = tanh(I);

        // jax.random.uniform(key, (B, GS)) with jax_threefry_partitionable=True
        // (default since JAX 0.4.36): per flat element c (64-bit iota),
        // (b1,b2) = threefry2x32(key, (c>>32, c&0xffffffff)); bits = b1 ^ b2.
        // Here size = 136448 < 2^32 so the high counter word is 0.
        const unsigned c = (unsigned)(b * GSZ + i);
        unsigned o0, o1;
        tf_dev(k0, k1, 0u, c, o0, o1);
        const unsigned bits = o0 ^ o1;
        const float u = __uint_as_float((bits >> 9) | 0x3f800000u) - 1.0f;
        const float r = u * 2.0f - 1.0f;  // exact in f32
        const double dr = (double)r;

        newv[i] = (th > dr) ? 1.0f : ((th < dr) ? -1.0f : 0.0f);
      }
      __syncthreads();
      for (int i = tid; i < GSZ; i += 256) m_lds[grp[i]] = newv[i];
      __syncthreads();
    }
  }

  for (int n = tid; n < NN; n += 256) out[(size_t)b * NN + n] = m_lds[n];
}

extern "C" void kernel_launch(void* const* d_in, const int* in_sizes, int n_in,
                              void* d_out, int out_size, void* d_ws, size_t ws_size,
                              hipStream_t stream) {
  const float* m0     = (const float*)d_in[0];
  const float* J      = (const float*)d_in[1];
  const float* H      = (const float*)d_in[2];
  const int*   groups = (const int*)d_in[3];
  // d_in[4] = sample_num (=10, hardcoded as NSWEEP)

  // Workspace layout: cols[NN*DMAX] int32 | vals[NN*DMAX] f32 | deg[NN] int32
  int*   cols = (int*)d_ws;
  float* vals = (float*)((char*)d_ws + (size_t)NN * DMAX * 4);
  int*   deg  = (int*)((char*)d_ws + (size_t)NN * DMAX * 8);

  // Host-side key schedule, jax_threefry_partitionable=True (fold-like split):
  // key(42) -> data (0, 42).
  // split(key, n)[i] = threefry2x32(key, (hi=0, lo=i)) -> (out0, out1).
  Keys keys;
  for (int t = 0; t < NSWEEP; ++t) {
    unsigned ik0, ik1;
    tf_host(0u, 42u, 0u, (unsigned)t, &ik0, &ik1);
    for (int g = 0; g < NGRP; ++g) {
      unsigned gk0, gk1;
      tf_host(ik0, ik1, 0u, (unsigned)g, &gk0, &gk1);
      keys.k0[t * NGRP + g] = gk0;
      keys.k1[t * NGRP + g] = gk1;
    }
  }

  build_ell<<<NN, 256, 0, stream>>>(J, cols, vals, deg);
  gibbs<<<BB, 256, 0, stream>>>(m0, H, groups, cols, vals, deg, (float*)d_out, keys);
}

// Round 3
// 955.172 us; speedup vs baseline: 1.7353x; 1.7353x over previous
//
#include <hip/hip_runtime.h>
#include <hip/hip_bf16.h>
#include <stdint.h>

// Problem constants (from reference: N=4264, B=256, NG=8, GS=533, SAMPLE_NUM=10)
#define NN 4264
#define BB 256
#define GSZ 533
#define NGRP 8
#define NSWEEP 10
#define NSTEP (NSWEEP * NGRP)
#define DMAX 64   // hard cap on row degree (Poisson(15): P(deg>64) ~ 1e-18)
#define DFIX 24   // fixed-unroll depth; zero-padded. P(deg>24) ~ 5e-3 -> rare tail

struct Keys { unsigned k0[NSTEP]; unsigned k1[NSTEP]; };

// ---- threefry2x32, exactly as JAX (20 rounds, key injections every 4) ----
#define TF_ROUND(x0, x1, r) { x0 += x1; x1 = (x1 << (r)) | (x1 >> (32 - (r))); x1 ^= x0; }
#define TF_BODY(K0, K1, C0, C1, O0, O1) {                                   \
  unsigned ks0 = (K0), ks1 = (K1), ks2 = (K0) ^ (K1) ^ 0x1BD11BDAu;          \
  unsigned x0 = (C0) + ks0, x1 = (C1) + ks1;                                 \
  TF_ROUND(x0, x1, 13) TF_ROUND(x0, x1, 15) TF_ROUND(x0, x1, 26) TF_ROUND(x0, x1, 6)  \
  x0 += ks1; x1 += ks2 + 1u;                                                 \
  TF_ROUND(x0, x1, 17) TF_ROUND(x0, x1, 29) TF_ROUND(x0, x1, 16) TF_ROUND(x0, x1, 24) \
  x0 += ks2; x1 += ks0 + 2u;                                                 \
  TF_ROUND(x0, x1, 13) TF_ROUND(x0, x1, 15) TF_ROUND(x0, x1, 26) TF_ROUND(x0, x1, 6)  \
  x0 += ks0; x1 += ks1 + 3u;                                                 \
  TF_ROUND(x0, x1, 17) TF_ROUND(x0, x1, 29) TF_ROUND(x0, x1, 16) TF_ROUND(x0, x1, 24) \
  x0 += ks1; x1 += ks2 + 4u;                                                 \
  TF_ROUND(x0, x1, 13) TF_ROUND(x0, x1, 15) TF_ROUND(x0, x1, 26) TF_ROUND(x0, x1, 6)  \
  x0 += ks2; x1 += ks0 + 5u;                                                 \
  (O0) = x0; (O1) = x1; }

static void tf_host(unsigned k0, unsigned k1, unsigned c0, unsigned c1,
                    unsigned* o0, unsigned* o1) {
  unsigned a, b;
  TF_BODY(k0, k1, c0, c1, a, b);
  *o0 = a; *o1 = b;
}

__device__ __forceinline__ void tf_dev(unsigned k0, unsigned k1, unsigned c0, unsigned c1,
                                       unsigned& o0, unsigned& o1) {
  TF_BODY(k0, k1, c0, c1, o0, o1);
}

// ---- Build transposed group-major ELL of J ----
// Row p = g*GSZ + i corresponds to node = groups[p]. Entry k of row p lives at
// ell[k*NN + p] as {col, val} (8 B) -> per-wave loads over consecutive p are
// perfectly coalesced in the gibbs kernel. Entries are ascending-column;
// rows zero-padded up to DFIX so the fixed unroll needs no bounds checks.
__global__ __launch_bounds__(256) void build_ell(const float* __restrict__ J,
                                                 const int* __restrict__ groups,
                                                 int2* __restrict__ ell,
                                                 int* __restrict__ deg) {
  const int p = blockIdx.x;
  const int node = groups[p];
  const int tid = threadIdx.x;
  __shared__ int s_cnt;
  __shared__ int wcnt[4];
  if (tid == 0) s_cnt = 0;
  __syncthreads();
  const float* Jr = J + (size_t)node * NN;
  for (int base = 0; base < NN; base += 256) {
    const int c = base + tid;
    const float v = (c < NN) ? Jr[c] : 0.0f;
    const bool nz = (v != 0.0f);
    const unsigned long long mask = __ballot(nz);
    const int wave = tid >> 6, lane = tid & 63;
    if (lane == 0) wcnt[wave] = __popcll(mask);
    __syncthreads();
    int off = s_cnt;
    for (int w = 0; w < wave; ++w) off += wcnt[w];
    const int rank = off + __popcll(mask & ((1ull << lane) - 1ull));
    if (nz && rank < DMAX) {
      ell[(size_t)rank * NN + p] = make_int2(c, __float_as_int(v));
    }
    __syncthreads();
    if (tid == 0) s_cnt += wcnt[0] + wcnt[1] + wcnt[2] + wcnt[3];
    __syncthreads();
  }
  int d = s_cnt;
  if (d > DMAX) d = DMAX;
  // zero-pad the fixed-unroll region
  for (int k = d + tid; k < DFIX; k += 256) ell[(size_t)k * NN + p] = make_int2(0, 0);
  if (tid == 0) deg[p] = d;
}

// ---- Full Gibbs chain: one workgroup per batch row (rows are independent) ----
// 576 threads = 9 waves: one node per thread per group-step.
__global__ __launch_bounds__(576) void gibbs(const float* __restrict__ m0,
                                             const float* __restrict__ H,
                                             const int* __restrict__ groups,
                                             const int2* __restrict__ ell,
                                             const int* __restrict__ deg,
                                             float* __restrict__ out,
                                             Keys keys) {
  __shared__ float m_lds[NN];
  const int b = blockIdx.x;
  const int i = threadIdx.x;
  const bool active = (i < GSZ);

  for (int n = i; n < NN; n += 576) m_lds[n] = m0[(size_t)b * NN + n];

  // Per-thread per-group preload (groups/H/deg are step-invariant).
  int nodeg[NGRP];
  float hg[NGRP];
  int dgg[NGRP];
  if (active) {
#pragma unroll
    for (int g = 0; g < NGRP; ++g) {
      const int p = g * GSZ + i;
      nodeg[g] = groups[p];
      hg[g] = H[nodeg[g]];
      dgg[g] = deg[p];
    }
  }
  __syncthreads();

  const unsigned c = (unsigned)(b * GSZ + i);

#pragma unroll 1
  for (int t = 0; t < NSWEEP; ++t) {
#pragma unroll
    for (int g = 0; g < NGRP; ++g) {
      const int step = t * NGRP + g;
      const unsigned k0 = keys.k0[step];
      const unsigned k1 = keys.k1[step];
      float nv = 0.0f;
      if (active) {
        const int2* ep = ell + (g * GSZ + i);
        float a0 = 0.0f, a1 = 0.0f, a2 = 0.0f, a3 = 0.0f;
#pragma unroll
        for (int k = 0; k < DFIX; k += 4) {
          const int2 p0 = ep[(k + 0) * NN];
          const int2 p1 = ep[(k + 1) * NN];
          const int2 p2 = ep[(k + 2) * NN];
          const int2 p3 = ep[(k + 3) * NN];
          a0 += __int_as_float(p0.y) * m_lds[p0.x];
          a1 += __int_as_float(p1.y) * m_lds[p1.x];
          a2 += __int_as_float(p2.y) * m_lds[p2.x];
          a3 += __int_as_float(p3.y) * m_lds[p3.x];
        }
        const int dg = dgg[g];
        if (dg > DFIX) {
          for (int k = DFIX; k < dg; ++k) {
            const int2 pr = ep[k * NN];
            a0 += __int_as_float(pr.y) * m_lds[pr.x];
          }
        }
        const float I = ((a0 + a1) + (a2 + a3)) + hg[g];

        // jax.random.uniform, threefry_partitionable: bits = xor-fold of
        // threefry2x32(key, (0, c)); r = u*2-1 exact in f32.
        unsigned o0, o1;
        tf_dev(k0, k1, 0u, c, o0, o1);
        const unsigned bits = o0 ^ o1;
        const float u = __uint_as_float((bits >> 9) | 0x3f800000u) - 1.0f;
        const float r = u * 2.0f - 1.0f;

        const float th = tanhf(I);
        const float d = th - r;
        if (__builtin_expect(fabsf(d) > 1e-4f, 1)) {
          // f32 error bound ~2e-6 << 1e-4 margin: decision == exact decision
          nv = (d > 0.0f) ? 1.0f : -1.0f;
        } else {
          // boundary-close: settle in f64 (products of f32*(+-1) are exact)
          double I64 = (double)hg[g];
          for (int k = 0; k < dg; ++k) {
            const int2 pr = ep[k * NN];
            I64 += (double)__int_as_float(pr.y) * (double)m_lds[pr.x];
          }
          const double diff = tanh(I64) - (double)r;
          nv = (diff > 0.0) ? 1.0f : ((diff < 0.0) ? -1.0f : 0.0f);
        }
      }
      __syncthreads();                 // all gathers done
      if (active) m_lds[nodeg[g]] = nv; // compute-all-then-set semantics
      __syncthreads();                 // scatter visible before next group
    }
  }

  for (int n = i; n < NN; n += 576) out[(size_t)b * NN + n] = m_lds[n];
}

extern "C" void kernel_launch(void* const* d_in, const int* in_sizes, int n_in,
                              void* d_out, int out_size, void* d_ws, size_t ws_size,
                              hipStream_t stream) {
  const float* m0     = (const float*)d_in[0];
  const float* J      = (const float*)d_in[1];
  const float* H      = (const float*)d_in[2];
  const int*   groups = (const int*)d_in[3];
  // d_in[4] = sample_num (=10, hardcoded as NSWEEP)

  // Workspace: ell[DMAX*NN] int2 (2.18 MB) | deg[NN] int32
  int2* ell = (int2*)d_ws;
  int*  deg = (int*)((char*)d_ws + (size_t)DMAX * NN * sizeof(int2));

  // Host-side key schedule, jax_threefry_partitionable=True (fold-like split):
  // key(42) -> (0, 42); split(key, n)[i] = threefry2x32(key, (0, i)).
  Keys keys;
  for (int t = 0; t < NSWEEP; ++t) {
    unsigned ik0, ik1;
    tf_host(0u, 42u, 0u, (unsigned)t, &ik0, &ik1);
    for (int g = 0; g < NGRP; ++g) {
      unsigned gk0, gk1;
      tf_host(ik0, ik1, 0u, (unsigned)g, &gk0, &gk1);
      keys.k0[t * NGRP + g] = gk0;
      keys.k1[t * NGRP + g] = gk1;
    }
  }

  build_ell<<<NN, 256, 0, stream>>>(J, groups, ell, deg);
  gibbs<<<BB, 576, 0, stream>>>(m0, H, groups, ell, deg, (float*)d_out, keys);
}

// Round 4
// 306.280 us; speedup vs baseline: 5.4118x; 3.1186x over previous
//
#include <hip/hip_runtime.h>
#include <hip/hip_bf16.h>
#include <stdint.h>

// Problem constants (from reference: N=4264, B=256, NG=8, GS=533, SAMPLE_NUM=10)
#define NN 4264
#define BB 256
#define GSZ 533
#define NGRP 8
#define NSWEEP 10
#define NSTEP (NSWEEP * NGRP)
#define DMAX 48   // exact-table cap (Poisson(15): P(deg>48) ~ 1e-11 per node)
#define DFIX 24   // packed fast-path depth, zero-padded; tail read from exact table

struct Keys { unsigned k0[NSTEP]; unsigned k1[NSTEP]; };

// ---- threefry2x32, exactly as JAX (20 rounds, key injections every 4) ----
#define TF_ROUND(x0, x1, r) { x0 += x1; x1 = (x1 << (r)) | (x1 >> (32 - (r))); x1 ^= x0; }
#define TF_BODY(K0, K1, C0, C1, O0, O1) {                                   \
  unsigned ks0 = (K0), ks1 = (K1), ks2 = (K0) ^ (K1) ^ 0x1BD11BDAu;          \
  unsigned x0 = (C0) + ks0, x1 = (C1) + ks1;                                 \
  TF_ROUND(x0, x1, 13) TF_ROUND(x0, x1, 15) TF_ROUND(x0, x1, 26) TF_ROUND(x0, x1, 6)  \
  x0 += ks1; x1 += ks2 + 1u;                                                 \
  TF_ROUND(x0, x1, 17) TF_ROUND(x0, x1, 29) TF_ROUND(x0, x1, 16) TF_ROUND(x0, x1, 24) \
  x0 += ks2; x1 += ks0 + 2u;                                                 \
  TF_ROUND(x0, x1, 13) TF_ROUND(x0, x1, 15) TF_ROUND(x0, x1, 26) TF_ROUND(x0, x1, 6)  \
  x0 += ks0; x1 += ks1 + 3u;                                                 \
  TF_ROUND(x0, x1, 17) TF_ROUND(x0, x1, 29) TF_ROUND(x0, x1, 16) TF_ROUND(x0, x1, 24) \
  x0 += ks1; x1 += ks2 + 4u;                                                 \
  TF_ROUND(x0, x1, 13) TF_ROUND(x0, x1, 15) TF_ROUND(x0, x1, 26) TF_ROUND(x0, x1, 6)  \
  x0 += ks2; x1 += ks0 + 5u;                                                 \
  (O0) = x0; (O1) = x1; }

static void tf_host(unsigned k0, unsigned k1, unsigned c0, unsigned c1,
                    unsigned* o0, unsigned* o1) {
  unsigned a, b;
  TF_BODY(k0, k1, c0, c1, a, b);
  *o0 = a; *o1 = b;
}

__device__ __forceinline__ void tf_dev(unsigned k0, unsigned k1, unsigned c0, unsigned c1,
                                       unsigned& o0, unsigned& o1) {
  TF_BODY(k0, k1, c0, c1, o0, o1);
}

// ---- Build tables: wave-per-row, no barriers ----
// Row p = g*GSZ + i -> node = groups[p].
// pack4[p*DFIX + k]  = (col << 16) | bf16_rne(val)   (fast path, zero-padded)
// exact8[p*DMAX + k] = {col, f32 val}                (fallback + tail, ascending col)
// marg[p] = 2^-9 * sum_{k<DFIX} |val| + 2e-5         (screen margin bound)
__global__ __launch_bounds__(256) void build_ell(const float* __restrict__ J,
                                                 const int* __restrict__ groups,
                                                 unsigned* __restrict__ pack4,
                                                 int2* __restrict__ exact8,
                                                 int* __restrict__ deg,
                                                 float* __restrict__ marg) {
  const int wv = threadIdx.x >> 6, lane = threadIdx.x & 63;
  const int p = blockIdx.x * 4 + wv;
  if (p >= NN) return;
  const int node = groups[p];
  const float* row = J + (size_t)node * NN;
  int cnt = 0;
  float asum = 0.0f;
  for (int base = 0; base < NN; base += 64) {
    const int c = base + lane;
    const float v = (c < NN) ? row[c] : 0.0f;
    const bool nz = (v != 0.0f);
    const unsigned long long mask = __ballot(nz);
    const int rank = cnt + __popcll(mask & ((1ull << lane) - 1ull));
    if (nz) {
      if (rank < DFIX) {
        const unsigned bits = __float_as_uint(v);
        const unsigned bf = (bits + 0x7fffu + ((bits >> 16) & 1u)) >> 16;  // RNE -> bf16
        pack4[(size_t)p * DFIX + rank] = ((unsigned)c << 16) | bf;
        asum += fabsf(v);
      }
      if (rank < DMAX) exact8[(size_t)p * DMAX + rank] = make_int2(c, __float_as_int(v));
    }
    cnt += __popcll(mask);
  }
  // zero-pad packed row
  for (int k = cnt + lane; k < DFIX; k += 64) pack4[(size_t)p * DFIX + k] = 0u;
  // wave-reduce abs-sum
  for (int s = 1; s < 64; s <<= 1) asum += __shfl_xor(asum, s, 64);
  if (lane == 0) {
    deg[p] = (cnt > DMAX) ? DMAX : cnt;
    marg[p] = asum * 0.001953125f + 2e-5f;  // 2^-9 * sum|v| + f32/tanhf slack
  }
}

// ---- Full Gibbs chain: one workgroup per batch row (rows are independent) ----
// 576 threads = 9 waves: one node per thread per group-step.
__global__ __launch_bounds__(576) void gibbs(const float* __restrict__ m0,
                                             const float* __restrict__ H,
                                             const int* __restrict__ groups,
                                             const unsigned* __restrict__ pack4,
                                             const int2* __restrict__ exact8,
                                             const int* __restrict__ deg,
                                             const float* __restrict__ marg,
                                             float* __restrict__ out,
                                             Keys keys) {
  __shared__ float m_lds[NN];
  const int b = blockIdx.x;
  const int i = threadIdx.x;
  const bool active = (i < GSZ);

  for (int n = i; n < NN; n += 576) m_lds[n] = m0[(size_t)b * NN + n];

  // Per-thread per-group preload (step-invariant).
  int nodeg[NGRP];
  float hg[NGRP], mgg[NGRP];
  int dgg[NGRP];
  if (active) {
#pragma unroll
    for (int g = 0; g < NGRP; ++g) {
      const int p = g * GSZ + i;
      nodeg[g] = groups[p];
      hg[g] = H[nodeg[g]];
      dgg[g] = deg[p];
      mgg[g] = marg[p];
    }
  }
  __syncthreads();

  const unsigned c = (unsigned)(b * GSZ + i);

#pragma unroll 1
  for (int t = 0; t < NSWEEP; ++t) {
#pragma unroll
    for (int g = 0; g < NGRP; ++g) {
      const int step = t * NGRP + g;
      const unsigned k0 = keys.k0[step];
      const unsigned k1 = keys.k1[step];
      float nv = 0.0f;
      if (active) {
        const int p = g * GSZ + i;
        // 24 packed entries = 6 contiguous uint4 (96 B/thread, coalesced per wave)
        const uint4* q = (const uint4*)(pack4 + (size_t)p * DFIX);
        uint4 w0 = q[0], w1 = q[1], w2 = q[2], w3 = q[3], w4 = q[4], w5 = q[5];
        float a0 = 0.0f, a1 = 0.0f, a2 = 0.0f, a3 = 0.0f;
#define ACC(W) \
        a0 += __uint_as_float((W).x << 16) * m_lds[(W).x >> 16]; \
        a1 += __uint_as_float((W).y << 16) * m_lds[(W).y >> 16]; \
        a2 += __uint_as_float((W).z << 16) * m_lds[(W).z >> 16]; \
        a3 += __uint_as_float((W).w << 16) * m_lds[(W).w >> 16];
        ACC(w0) ACC(w1) ACC(w2) ACC(w3) ACC(w4) ACC(w5)
#undef ACC
        const int dg = dgg[g];
        const int2* ep = exact8 + (size_t)p * DMAX;
        if (__builtin_expect(dg > DFIX, 0)) {
          for (int k = DFIX; k < dg; ++k) {
            const int2 e = ep[k];
            a0 += __int_as_float(e.y) * m_lds[e.x];
          }
        }
        const float I = ((a0 + a1) + (a2 + a3)) + hg[g];

        // jax.random.uniform, threefry_partitionable: bits = xor-fold of
        // threefry2x32(key, (0, c)); r = u*2-1 exact in f32.
        unsigned o0, o1;
        tf_dev(k0, k1, 0u, c, o0, o1);
        const unsigned bits = o0 ^ o1;
        const float u = __uint_as_float((bits >> 9) | 0x3f800000u) - 1.0f;
        const float r = u * 2.0f - 1.0f;

        const float th = tanhf(I);
        const float d = th - r;
        if (__builtin_expect(fabsf(d) > mgg[g], 1)) {
          // |tanhf(I_fast) - tanh64(I_exact)| <= marg  ->  sign matches exact
          nv = (d > 0.0f) ? 1.0f : -1.0f;
        } else {
          // boundary-close: settle in f64 from exact f32 table (ascending col)
          double I64 = (double)hg[g];
          for (int k = 0; k < dg; ++k) {
            const int2 e = ep[k];
            I64 += (double)__int_as_float(e.y) * (double)m_lds[e.x];
          }
          const double diff = tanh(I64) - (double)r;
          nv = (diff > 0.0) ? 1.0f : ((diff < 0.0) ? -1.0f : 0.0f);
        }
      }
      __syncthreads();                  // all gathers done
      if (active) m_lds[nodeg[g]] = nv; // compute-all-then-set semantics
      __syncthreads();                  // scatter visible before next group
    }
  }

  for (int n = i; n < NN; n += 576) out[(size_t)b * NN + n] = m_lds[n];
}

extern "C" void kernel_launch(void* const* d_in, const int* in_sizes, int n_in,
                              void* d_out, int out_size, void* d_ws, size_t ws_size,
                              hipStream_t stream) {
  const float* m0     = (const float*)d_in[0];
  const float* J      = (const float*)d_in[1];
  const float* H      = (const float*)d_in[2];
  const int*   groups = (const int*)d_in[3];
  // d_in[4] = sample_num (=10, hardcoded as NSWEEP)

  // Workspace: pack4[NN*DFIX] u32 (409 KB) | exact8[NN*DMAX] int2 (1.64 MB)
  //          | deg[NN] i32 | marg[NN] f32   -> total ~2.08 MB
  char* ws = (char*)d_ws;
  unsigned* pack4  = (unsigned*)ws;                     ws += (size_t)NN * DFIX * 4;
  int2*     exact8 = (int2*)ws;                         ws += (size_t)NN * DMAX * 8;
  int*      deg    = (int*)ws;                          ws += (size_t)NN * 4;
  float*    marg   = (float*)ws;

  // Host-side key schedule, jax_threefry_partitionable=True (fold-like split):
  // key(42) -> (0, 42); split(key, n)[i] = threefry2x32(key, (0, i)).
  Keys keys;
  for (int t = 0; t < NSWEEP; ++t) {
    unsigned ik0, ik1;
    tf_host(0u, 42u, 0u, (unsigned)t, &ik0, &ik1);
    for (int g = 0; g < NGRP; ++g) {
      unsigned gk0, gk1;
      tf_host(ik0, ik1, 0u, (unsigned)g, &gk0, &gk1);
      keys.k0[t * NGRP + g] = gk0;
      keys.k1[t * NGRP + g] = gk1;
    }
  }

  build_ell<<<(NN + 3) / 4, 256, 0, stream>>>(J, groups, pack4, exact8, deg, marg);
  gibbs<<<BB, 576, 0, stream>>>(m0, H, groups, pack4, exact8, deg, marg,
                                (float*)d_out, keys);
}

// Round 5
// 276.155 us; speedup vs baseline: 6.0021x; 1.1091x over previous
//
#include <hip/hip_runtime.h>
#include <hip/hip_bf16.h>
#include <stdint.h>

// Problem constants (from reference: N=4264, B=256, NG=8, GS=533, SAMPLE_NUM=10)
#define NN 4264
#define BB 256
#define GSZ 533
#define NGRP 8
#define NSWEEP 10
#define NSTEP (NSWEEP * NGRP)
#define DMAX 48   // exact-table cap (Poisson(15): P(deg>48) ~ 1e-11 per node)
#define DFIX 24   // packed fast-path depth, zero-padded; tail read from exact table
#define NF4 1066  // NN/4 float4s per row (17056 B, 16B-aligned)

struct Keys { unsigned k0[NSTEP]; unsigned k1[NSTEP]; };

// ---- threefry2x32, exactly as JAX (20 rounds, key injections every 4) ----
#define TF_ROUND(x0, x1, r) { x0 += x1; x1 = (x1 << (r)) | (x1 >> (32 - (r))); x1 ^= x0; }
#define TF_BODY(K0, K1, C0, C1, O0, O1) {                                   \
  unsigned ks0 = (K0), ks1 = (K1), ks2 = (K0) ^ (K1) ^ 0x1BD11BDAu;          \
  unsigned x0 = (C0) + ks0, x1 = (C1) + ks1;                                 \
  TF_ROUND(x0, x1, 13) TF_ROUND(x0, x1, 15) TF_ROUND(x0, x1, 26) TF_ROUND(x0, x1, 6)  \
  x0 += ks1; x1 += ks2 + 1u;                                                 \
  TF_ROUND(x0, x1, 17) TF_ROUND(x0, x1, 29) TF_ROUND(x0, x1, 16) TF_ROUND(x0, x1, 24) \
  x0 += ks2; x1 += ks0 + 2u;                                                 \
  TF_ROUND(x0, x1, 13) TF_ROUND(x0, x1, 15) TF_ROUND(x0, x1, 26) TF_ROUND(x0, x1, 6)  \
  x0 += ks0; x1 += ks1 + 3u;                                                 \
  TF_ROUND(x0, x1, 17) TF_ROUND(x0, x1, 29) TF_ROUND(x0, x1, 16) TF_ROUND(x0, x1, 24) \
  x0 += ks1; x1 += ks2 + 4u;                                                 \
  TF_ROUND(x0, x1, 13) TF_ROUND(x0, x1, 15) TF_ROUND(x0, x1, 26) TF_ROUND(x0, x1, 6)  \
  x0 += ks2; x1 += ks0 + 5u;                                                 \
  (O0) = x0; (O1) = x1; }

static void tf_host(unsigned k0, unsigned k1, unsigned c0, unsigned c1,
                    unsigned* o0, unsigned* o1) {
  unsigned a, b;
  TF_BODY(k0, k1, c0, c1, a, b);
  *o0 = a; *o1 = b;
}

__device__ __forceinline__ void tf_dev(unsigned k0, unsigned k1, unsigned c0, unsigned c1,
                                       unsigned& o0, unsigned& o1) {
  TF_BODY(k0, k1, c0, c1, o0, o1);
}

// ---- Build tables: wave-per-row, float4 scan, no barriers ----
// Row p = g*GSZ + i -> node = groups[p].
// pack4[p*DFIX + k]  = (bf16_rne(val) << 16) | (col << 2)  (fast path, zero-padded;
//                      low half is the LDS *byte* offset of m[col])
// exact8[p*DMAX + k] = {col, f32 val}                      (fallback + tail, ascending col)
// marg[p] = 2^-9 * sum_{k<DFIX} |val| + 2e-5               (screen margin bound)
__global__ __launch_bounds__(256) void build_ell(const float* __restrict__ J,
                                                 const int* __restrict__ groups,
                                                 unsigned* __restrict__ pack4,
                                                 int2* __restrict__ exact8,
                                                 int* __restrict__ deg,
                                                 float* __restrict__ marg) {
  const int wv = threadIdx.x >> 6, lane = threadIdx.x & 63;
  const int p = blockIdx.x * 4 + wv;
  if (p >= NN) return;
  const int node = groups[p];
  const float4* row = (const float4*)(J + (size_t)node * NN);  // NF4 float4s, 16B-aligned
  int cnt = 0;
  float asum = 0.0f;
  for (int it = 0; it < (NF4 + 63) / 64; ++it) {
    const int q = it * 64 + lane;
    float4 v;
    if (q < NF4) v = row[q];
    else         v = make_float4(0.0f, 0.0f, 0.0f, 0.0f);
    const int c0 = q * 4;
    // component-wise ballot compaction preserves exact ascending-column order
#define COMP(X, CIDX) {                                                        \
      const bool nz = ((X) != 0.0f);                                           \
      const unsigned long long mk = __ballot(nz);                              \
      const int rk = cnt + __popcll(mk & ((1ull << lane) - 1ull));             \
      if (nz) {                                                                \
        if (rk < DFIX) {                                                       \
          const unsigned bits = __float_as_uint(X);                            \
          const unsigned bf = (bits + 0x7fffu + ((bits >> 16) & 1u)) >> 16;    \
          pack4[(size_t)p * DFIX + rk] = (bf << 16) | ((unsigned)(CIDX) << 2); \
          asum += fabsf(X);                                                    \
        }                                                                      \
        if (rk < DMAX)                                                         \
          exact8[(size_t)p * DMAX + rk] = make_int2((CIDX), __float_as_int(X));\
      }                                                                        \
      cnt += __popcll(mk); }
    COMP(v.x, c0 + 0) COMP(v.y, c0 + 1) COMP(v.z, c0 + 2) COMP(v.w, c0 + 3)
#undef COMP
  }
  // zero-pad packed row
  for (int k = cnt + lane; k < DFIX; k += 64) pack4[(size_t)p * DFIX + k] = 0u;
  // wave-reduce abs-sum
  for (int s = 1; s < 64; s <<= 1) asum += __shfl_xor(asum, s, 64);
  if (lane == 0) {
    deg[p] = (cnt > DMAX) ? DMAX : cnt;
    marg[p] = asum * 0.001953125f + 2e-5f;  // 2^-9 * sum|v| + f32/tanhf slack
  }
}

// ---- Full Gibbs chain: one workgroup per batch row (rows are independent) ----
// 576 threads = 9 waves: one node per thread per group-step.
__global__ __launch_bounds__(576) void gibbs(const float* __restrict__ m0,
                                             const float* __restrict__ H,
                                             const int* __restrict__ groups,
                                             const unsigned* __restrict__ pack4,
                                             const int2* __restrict__ exact8,
                                             const int* __restrict__ deg,
                                             const float* __restrict__ marg,
                                             float* __restrict__ out,
                                             Keys keys) {
  __shared__ float m_lds[NN];
  const int b = blockIdx.x;
  const int i = threadIdx.x;
  const bool active = (i < GSZ);

  for (int n = i; n < NN; n += 576) m_lds[n] = m0[(size_t)b * NN + n];

  // Per-thread per-group preload (step-invariant).
  int nodeg[NGRP];
  float hg[NGRP], mgg[NGRP];
  int dgg[NGRP];
  if (active) {
#pragma unroll
    for (int g = 0; g < NGRP; ++g) {
      const int p = g * GSZ + i;
      nodeg[g] = groups[p];
      hg[g] = H[nodeg[g]];
      dgg[g] = deg[p];
      mgg[g] = marg[p];
    }
  }
  __syncthreads();

  const unsigned c = (unsigned)(b * GSZ + i);

#pragma unroll 1
  for (int t = 0; t < NSWEEP; ++t) {
#pragma unroll
    for (int g = 0; g < NGRP; ++g) {
      const int step = t * NGRP + g;
      const unsigned k0 = keys.k0[step];
      const unsigned k1 = keys.k1[step];
      float nv = 0.0f;
      if (active) {
        const int p = g * GSZ + i;
        // 24 packed entries = 6 contiguous uint4 (96 B/thread, coalesced per wave)
        const uint4* q = (const uint4*)(pack4 + (size_t)p * DFIX);
        uint4 w0 = q[0], w1 = q[1], w2 = q[2], w3 = q[3], w4 = q[4], w5 = q[5];
        float a0 = 0.0f, a1 = 0.0f, a2 = 0.0f, a3 = 0.0f;
        // value = high-16 bits as f32 (bf16<<16); addr = low-16 = byte offset
#define MV(W)  (*(const float*)((const char*)m_lds + ((W) & 0xFFFCu)))
#define ACC(W) \
        a0 += __uint_as_float((W).x & 0xFFFF0000u) * MV((W).x); \
        a1 += __uint_as_float((W).y & 0xFFFF0000u) * MV((W).y); \
        a2 += __uint_as_float((W).z & 0xFFFF0000u) * MV((W).z); \
        a3 += __uint_as_float((W).w & 0xFFFF0000u) * MV((W).w);
        ACC(w0) ACC(w1) ACC(w2) ACC(w3) ACC(w4) ACC(w5)
#undef ACC
#undef MV
        const int dg = dgg[g];
        const int2* ep = exact8 + (size_t)p * DMAX;
        if (__builtin_expect(dg > DFIX, 0)) {
          for (int k = DFIX; k < dg; ++k) {
            const int2 e = ep[k];
            a0 += __int_as_float(e.y) * m_lds[e.x];
          }
        }
        const float I = ((a0 + a1) + (a2 + a3)) + hg[g];

        // jax.random.uniform, threefry_partitionable: bits = xor-fold of
        // threefry2x32(key, (0, c)); r = u*2-1 exact in f32.
        unsigned o0, o1;
        tf_dev(k0, k1, 0u, c, o0, o1);
        const unsigned bits = o0 ^ o1;
        const float u = __uint_as_float((bits >> 9) | 0x3f800000u) - 1.0f;
        const float r = u * 2.0f - 1.0f;

        const float th = tanhf(I);
        const float d = th - r;
        if (__builtin_expect(fabsf(d) > mgg[g], 1)) {
          // |tanhf(I_fast) - tanh64(I_exact)| <= marg  ->  sign matches exact
          nv = (d > 0.0f) ? 1.0f : -1.0f;
        } else {
          // boundary-close: settle in f64 from exact f32 table (ascending col)
          double I64 = (double)hg[g];
          for (int k = 0; k < dg; ++k) {
            const int2 e = ep[k];
            I64 += (double)__int_as_float(e.y) * (double)m_lds[e.x];
          }
          const double diff = tanh(I64) - (double)r;
          nv = (diff > 0.0) ? 1.0f : ((diff < 0.0) ? -1.0f : 0.0f);
        }
      }
      __syncthreads();                  // all gathers done
      if (active) m_lds[nodeg[g]] = nv; // compute-all-then-set semantics
      __syncthreads();                  // scatter visible before next group
    }
  }

  for (int n = i; n < NN; n += 576) out[(size_t)b * NN + n] = m_lds[n];
}

extern "C" void kernel_launch(void* const* d_in, const int* in_sizes, int n_in,
                              void* d_out, int out_size, void* d_ws, size_t ws_size,
                              hipStream_t stream) {
  const float* m0     = (const float*)d_in[0];
  const float* J      = (const float*)d_in[1];
  const float* H      = (const float*)d_in[2];
  const int*   groups = (const int*)d_in[3];
  // d_in[4] = sample_num (=10, hardcoded as NSWEEP)

  // Workspace: pack4[NN*DFIX] u32 (409 KB) | exact8[NN*DMAX] int2 (1.64 MB)
  //          | deg[NN] i32 | marg[NN] f32   -> total ~2.08 MB
  char* ws = (char*)d_ws;
  unsigned* pack4  = (unsigned*)ws;                     ws += (size_t)NN * DFIX * 4;
  int2*     exact8 = (int2*)ws;                         ws += (size_t)NN * DMAX * 8;
  int*      deg    = (int*)ws;                          ws += (size_t)NN * 4;
  float*    marg   = (float*)ws;

  // Host-side key schedule, jax_threefry_partitionable=True (fold-like split):
  // key(42) -> (0, 42); split(key, n)[i] = threefry2x32(key, (0, i)).
  Keys keys;
  for (int t = 0; t < NSWEEP; ++t) {
    unsigned ik0, ik1;
    tf_host(0u, 42u, 0u, (unsigned)t, &ik0, &ik1);
    for (int g = 0; g < NGRP; ++g) {
      unsigned gk0, gk1;
      tf_host(ik0, ik1, 0u, (unsigned)g, &gk0, &gk1);
      keys.k0[t * NGRP + g] = gk0;
      keys.k1[t * NGRP + g] = gk1;
    }
  }

  build_ell<<<(NN + 3) / 4, 256, 0, stream>>>(J, groups, pack4, exact8, deg, marg);
  gibbs<<<BB, 576, 0, stream>>>(m0, H, groups, pack4, exact8, deg, marg,
                                (float*)d_out, keys);
}